// Round 2
// baseline (206.818 us; speedup 1.0000x reference)
//
#include <hip/hip_runtime.h>

#define N_IN   128
#define LAYERS 6
#define N_H    320
#define DEG    32
#define N_OUT  18
#define N_TOTAL (N_IN + LAYERS * N_H)   // 2048
#define BB     4                        // batch elements per block

__device__ __forceinline__ float fast_tanh(float x) {
    // tanh(x) = 1 - 2/(exp(2x)+1); exact at +/-inf limits, ~1e-6 abs error
    float e = __expf(2.0f * x);
    return 1.0f - 2.0f * __builtin_amdgcn_rcpf(e + 1.0f);
}

// pack two floats into one dword of 2x bf16 (round-to-nearest-even)
__device__ __forceinline__ unsigned int pack_bf16x2(float lo, float hi) {
    unsigned int ulo = __float_as_uint(lo);
    unsigned int uhi = __float_as_uint(hi);
    ulo = (ulo + 0x7fffu + ((ulo >> 16) & 1u)) >> 16;
    uhi = (uhi + 0x7fffu + ((uhi >> 16) & 1u)) & 0xffff0000u;
    return ulo | uhi;
}
__device__ __forceinline__ float bf_lo(unsigned int d) { return __uint_as_float(d << 16); }
__device__ __forceinline__ float bf_hi(unsigned int d) { return __uint_as_float(d & 0xffff0000u); }

__global__ __launch_bounds__(N_H) void policy_kernel(
    const float* __restrict__ obs,      // [B][N_IN]
    const int*   __restrict__ hid_src,  // [L][N_H][DEG]
    const float* __restrict__ hid_w,    // [L][N_H][DEG]
    const float* __restrict__ hid_b,    // [L][N_H]
    const int*   __restrict__ out_src,  // [N_OUT][DEG]
    const float* __restrict__ out_w,    // [N_OUT][DEG]
    const float* __restrict__ out_b,    // [N_OUT]
    float*       __restrict__ out)      // [B][N_OUT]
{
    // acts row r = 8 bytes: dword0 = bf16(b0)|bf16(b1)<<16, dword1 = bf16(b2)|bf16(b3)<<16
    // 16 KB -> wave-cap-limited 6 blocks/CU (30 waves) for latency hiding.
    __shared__ alignas(16) unsigned int sA[N_TOTAL * 2];

    const int tid = threadIdx.x;
    const int b0  = blockIdx.x * BB;

    // Stage obs -> sA rows [0, N_IN): thread i packs row i from 4 batch rows.
    if (tid < N_IN) {
        float v0 = obs[(b0 + 0) * N_IN + tid];
        float v1 = obs[(b0 + 1) * N_IN + tid];
        float v2 = obs[(b0 + 2) * N_IN + tid];
        float v3 = obs[(b0 + 3) * N_IN + tid];
        uint2 d;
        d.x = pack_bf16x2(v0, v1);
        d.y = pack_bf16x2(v2, v3);
        *(uint2*)(sA + 2 * tid) = d;
    }
    __syncthreads();

    const int n = tid;  // one hidden unit per thread (blockDim == N_H)

    for (int l = 0; l < LAYERS; ++l) {
        const int4*   src4 = (const int4*)  (hid_src + (l * N_H + n) * DEG);
        const float4* w4   = (const float4*)(hid_w   + (l * N_H + n) * DEG);
        float ax = 0.f, ay = 0.f, az = 0.f, aw = 0.f;
        #pragma unroll
        for (int q = 0; q < DEG / 4; ++q) {
            int4   s = src4[q];
            float4 w = w4[q];
            // issue all 4 ds_read_b64 before consuming (batched waitcnt)
            uint2 g0 = *(const uint2*)(sA + 2 * s.x);
            uint2 g1 = *(const uint2*)(sA + 2 * s.y);
            uint2 g2 = *(const uint2*)(sA + 2 * s.z);
            uint2 g3 = *(const uint2*)(sA + 2 * s.w);
            ax += bf_lo(g0.x) * w.x + bf_lo(g1.x) * w.y + bf_lo(g2.x) * w.z + bf_lo(g3.x) * w.w;
            ay += bf_hi(g0.x) * w.x + bf_hi(g1.x) * w.y + bf_hi(g2.x) * w.z + bf_hi(g3.x) * w.w;
            az += bf_lo(g0.y) * w.x + bf_lo(g1.y) * w.y + bf_lo(g2.y) * w.z + bf_lo(g3.y) * w.w;
            aw += bf_hi(g0.y) * w.x + bf_hi(g1.y) * w.y + bf_hi(g2.y) * w.z + bf_hi(g3.y) * w.w;
        }
        float bias = hid_b[l * N_H + n];
        float h0 = fast_tanh(ax + bias);
        float h1 = fast_tanh(ay + bias);
        float h2 = fast_tanh(az + bias);
        float h3 = fast_tanh(aw + bias);
        uint2 d;
        d.x = pack_bf16x2(h0, h1);
        d.y = pack_bf16x2(h2, h3);
        // writes go to rows this layer never reads; one barrier per layer suffices.
        *(uint2*)(sA + 2 * (N_IN + l * N_H + n)) = d;
        __syncthreads();
    }

    // Output layer: 18 units (fp32 out)
    if (n < N_OUT) {
        const int4*   src4 = (const int4*)  (out_src + n * DEG);
        const float4* w4   = (const float4*)(out_w   + n * DEG);
        float ax = 0.f, ay = 0.f, az = 0.f, aw = 0.f;
        #pragma unroll
        for (int q = 0; q < DEG / 4; ++q) {
            int4   s = src4[q];
            float4 w = w4[q];
            uint2 g0 = *(const uint2*)(sA + 2 * s.x);
            uint2 g1 = *(const uint2*)(sA + 2 * s.y);
            uint2 g2 = *(const uint2*)(sA + 2 * s.z);
            uint2 g3 = *(const uint2*)(sA + 2 * s.w);
            ax += bf_lo(g0.x) * w.x + bf_lo(g1.x) * w.y + bf_lo(g2.x) * w.z + bf_lo(g3.x) * w.w;
            ay += bf_hi(g0.x) * w.x + bf_hi(g1.x) * w.y + bf_hi(g2.x) * w.z + bf_hi(g3.x) * w.w;
            az += bf_lo(g0.y) * w.x + bf_lo(g1.y) * w.y + bf_lo(g2.y) * w.z + bf_lo(g3.y) * w.w;
            aw += bf_hi(g0.y) * w.x + bf_hi(g1.y) * w.y + bf_hi(g2.y) * w.z + bf_hi(g3.y) * w.w;
        }
        float bias = out_b[n];
        out[(b0 + 0) * N_OUT + n] = fast_tanh(ax + bias);
        out[(b0 + 1) * N_OUT + n] = fast_tanh(ay + bias);
        out[(b0 + 2) * N_OUT + n] = fast_tanh(az + bias);
        out[(b0 + 3) * N_OUT + n] = fast_tanh(aw + bias);
    }
}

extern "C" void kernel_launch(void* const* d_in, const int* in_sizes, int n_in,
                              void* d_out, int out_size, void* d_ws, size_t ws_size,
                              hipStream_t stream) {
    const float* obs     = (const float*)d_in[0];
    const int*   hid_src = (const int*)  d_in[1];
    const float* hid_w   = (const float*)d_in[2];
    const float* hid_b   = (const float*)d_in[3];
    const int*   out_src = (const int*)  d_in[4];
    const float* out_w   = (const float*)d_in[5];
    const float* out_b   = (const float*)d_in[6];
    float* out = (float*)d_out;

    const int batch = in_sizes[0] / N_IN;   // 8192
    policy_kernel<<<batch / BB, N_H, 0, stream>>>(
        obs, hid_src, hid_w, hid_b, out_src, out_w, out_b, out);
}

// Round 3
// 144.133 us; speedup vs baseline: 1.4349x; 1.4349x over previous
//
#include <hip/hip_runtime.h>

#define N_IN   128
#define LAYERS 6
#define N_H    320
#define DEG    32
#define N_OUT  18
#define N_TOTAL (N_IN + LAYERS * N_H)   // 2048
#define BB     4                        // batch elements per block
#define HID_ELEMS (LAYERS * N_H * DEG)  // 61440
#define OUT_OFF   HID_ELEMS
#define TOT_ELEMS (HID_ELEMS + N_OUT * DEG)  // 62016

__device__ __forceinline__ float fast_tanh(float x) {
    float e = __expf(2.0f * x);
    return 1.0f - 2.0f * __builtin_amdgcn_rcpf(e + 1.0f);
}

// Fuse index + weight into one dword: hi16 = bf16(w), lo16 = idx*16 (LDS byte offset).
// idx < 2048 -> idx*16 < 32768 fits in 16 bits.
__global__ __launch_bounds__(256) void pack_kernel(
    const int* __restrict__ hid_src, const float* __restrict__ hid_w,
    const int* __restrict__ out_src, const float* __restrict__ out_w,
    unsigned int* __restrict__ fused)
{
    int i = blockIdx.x * 256 + threadIdx.x;
    if (i >= TOT_ELEMS) return;
    int idx; float w;
    if (i < HID_ELEMS) { idx = hid_src[i]; w = hid_w[i]; }
    else               { idx = out_src[i - HID_ELEMS]; w = out_w[i - HID_ELEMS]; }
    unsigned int uw = __float_as_uint(w);
    uw = (uw + 0x7fffu + ((uw >> 16) & 1u)) & 0xffff0000u;  // bf16 RNE, kept in hi bits
    fused[i] = uw | (unsigned int)(idx << 4);
}

__device__ __forceinline__ void dot4(const float* acts, unsigned int u,
                                     float& ax, float& ay, float& az, float& aw) {
    const float4 a = *(const float4*)((const char*)acts + (u & 0xffffu));
    const float  w = __uint_as_float(u & 0xffff0000u);
    ax += a.x * w; ay += a.y * w; az += a.z * w; aw += a.w * w;
}

__global__ __launch_bounds__(N_H, 5) void policy_kernel(
    const float* __restrict__ obs,       // [B][N_IN]
    const unsigned int* __restrict__ fused,  // packed idx+w
    const float* __restrict__ hid_b,     // [L][N_H]
    const float* __restrict__ out_b,     // [N_OUT]
    float*       __restrict__ out)       // [B][N_OUT]
{
    __shared__ alignas(16) float acts[N_TOTAL * BB];   // 32 KB

    const int tid = threadIdx.x;
    const int b0  = blockIdx.x * BB;
    const int n   = tid;
    const uint4* ftab = (const uint4*)fused;   // 8 uint4 per unit

    // Prefetch layer 0's fused idx/w while staging obs.
    uint4 f[8];
    #pragma unroll
    for (int q = 0; q < 8; ++q) f[q] = ftab[n * 8 + q];

    for (int idx = tid; idx < N_IN * BB; idx += N_H) {
        int j = idx >> 7;            // batch slot
        int i = idx & (N_IN - 1);    // feature (coalesced global read)
        acts[i * BB + j] = obs[(b0 + j) * N_IN + i];
    }
    __syncthreads();

    for (int l = 0; l < LAYERS; ++l) {
        float ax = 0.f, ay = 0.f, az = 0.f, aw = 0.f;
        #pragma unroll
        for (int q = 0; q < 8; ++q) {
            dot4(acts, f[q].x, ax, ay, az, aw);
            dot4(acts, f[q].y, ax, ay, az, aw);
            dot4(acts, f[q].z, ax, ay, az, aw);
            dot4(acts, f[q].w, ax, ay, az, aw);
        }
        // Prefetch next layer (or output layer) before the barrier so global
        // latency overlaps the barrier wait.
        int nbase = (l + 1 < LAYERS) ? ((l + 1) * N_H + n) * 8
                                     : (OUT_OFF / 4 + (n < N_OUT ? n * 8 : 0));
        #pragma unroll
        for (int q = 0; q < 8; ++q) f[q] = ftab[nbase + q];

        float bias = hid_b[l * N_H + n];
        float4 h;
        h.x = fast_tanh(ax + bias);
        h.y = fast_tanh(ay + bias);
        h.z = fast_tanh(az + bias);
        h.w = fast_tanh(aw + bias);
        *(float4*)(acts + (N_IN + l * N_H + n) * BB) = h;
        __syncthreads();
    }

    if (n < N_OUT) {
        float ax = 0.f, ay = 0.f, az = 0.f, aw = 0.f;
        #pragma unroll
        for (int q = 0; q < 8; ++q) {
            dot4(acts, f[q].x, ax, ay, az, aw);
            dot4(acts, f[q].y, ax, ay, az, aw);
            dot4(acts, f[q].z, ax, ay, az, aw);
            dot4(acts, f[q].w, ax, ay, az, aw);
        }
        float bias = out_b[n];
        out[(b0 + 0) * N_OUT + n] = fast_tanh(ax + bias);
        out[(b0 + 1) * N_OUT + n] = fast_tanh(ay + bias);
        out[(b0 + 2) * N_OUT + n] = fast_tanh(az + bias);
        out[(b0 + 3) * N_OUT + n] = fast_tanh(aw + bias);
    }
}

extern "C" void kernel_launch(void* const* d_in, const int* in_sizes, int n_in,
                              void* d_out, int out_size, void* d_ws, size_t ws_size,
                              hipStream_t stream) {
    const float* obs     = (const float*)d_in[0];
    const int*   hid_src = (const int*)  d_in[1];
    const float* hid_w   = (const float*)d_in[2];
    const float* hid_b   = (const float*)d_in[3];
    const int*   out_src = (const int*)  d_in[4];
    const float* out_w   = (const float*)d_in[5];
    const float* out_b   = (const float*)d_in[6];
    float* out = (float*)d_out;
    unsigned int* fused = (unsigned int*)d_ws;   // 248 KB needed

    const int batch = in_sizes[0] / N_IN;   // 8192

    pack_kernel<<<(TOT_ELEMS + 255) / 256, 256, 0, stream>>>(
        hid_src, hid_w, out_src, out_w, fused);
    policy_kernel<<<batch / BB, N_H, 0, stream>>>(
        obs, fused, hid_b, out_b, out);
}